// Round 11
// baseline (320.511 us; speedup 1.0000x reference)
//
#include <hip/hip_runtime.h>
#include <hip/hip_bf16.h>
#include <math.h>

#define N_NODES 50000
#define N_EDGES 800000
#define ET (N_EDGES + N_NODES)   // with self loops = 850000
#define F0 128
#define H1 8
#define C1 32
#define D1 (H1*C1)               // 256
#define C2 32
#define C3 64
#define CAP 128                   // fixed bucket capacity (max deg ~45 for this input; 128 = huge margin)
#define SCATB 512                 // scatter-role blocks prepended to gemm1's grid

typedef unsigned short u16;
typedef unsigned int u32;
typedef __attribute__((ext_vector_type(8))) short short8;
typedef __attribute__((ext_vector_type(4))) float f32x4;

__device__ __forceinline__ float lrelu(float x) { return x >= 0.f ? x : 0.2f * x; }
__device__ __forceinline__ float eluf(float x)  { return x > 0.f ? x : (expf(x) - 1.f); }

__device__ __forceinline__ u16 f2bf(float f) {
    u32 u = __float_as_uint(f);
    return (u16)((u + 0x7FFFu + ((u >> 16) & 1u)) >> 16);   // RNE
}
__device__ __forceinline__ u32 pack2bf(float lo, float hi) {
    return ((u32)f2bf(hi) << 16) | (u32)f2bf(lo);
}
__device__ __forceinline__ float4 bf4_to_f4(uint2 v) {
    float4 r;
    r.x = __uint_as_float(v.x << 16);
    r.y = __uint_as_float(v.x & 0xFFFF0000u);
    r.z = __uint_as_float(v.y << 16);
    r.w = __uint_as_float(v.y & 0xFFFF0000u);
    return r;
}

// ---------------- prep: zero cnt + weight transposes/conversions (one kernel, no deps) ----------------

__global__ void prep_kernel(const float* __restrict__ W1, const float* __restrict__ W2,
                            const float* __restrict__ W3,
                            u16* __restrict__ W1t, u16* __restrict__ W2t, u16* __restrict__ W3t,
                            int* __restrict__ cnt) {
    int t = blockIdx.x * 256 + threadIdx.x;
    if (t < N_NODES) cnt[t] = 0;
    if (t < F0 * D1) {            // W1[128][256] -> W1t[256][128] bf16 (n-major, coalesced writes)
        int n = t >> 7, k = t & 127;
        W1t[n * F0 + k] = f2bf(W1[(size_t)k * D1 + n]);
    }
    if (t < D1 * C2) {            // W2[256][32] -> W2t[32][256]
        int k = t >> 5, n = t & 31;
        W2t[n * D1 + k] = f2bf(W2[t]);
    }
    if (t < C2 * C3) {            // W3[32][64] -> W3t[64][32]
        int k = t >> 6, n = t & 63;
        W3t[n * C2 + k] = f2bf(W3[t]);
    }
}

// ---------------- gemm1 + fused edge scatter (block-role split) ----------------
// Blocks [0,SCATB): edge scatter (atomic-latency-bound, idle pipes) -- co-resident with
// gemm blocks on the same CUs, so the atomic drain hides under MFMA work.
// Blocks [SCATB, ...): the proven gemm1 (x[M,128] f32 @ W1t bf16 -> h1b bf16 + fused alpha).

#define WKS 136

__global__ __launch_bounds__(512, 2) void gemm1_scat(const u16* __restrict__ W1t,
                                                     const float* __restrict__ x,
                                                     const float* __restrict__ aS1,
                                                     const float* __restrict__ aD1,
                                                     u16* __restrict__ h1b,
                                                     float* __restrict__ as,
                                                     float* __restrict__ ad, int M,
                                                     const int* __restrict__ srcArr,
                                                     const int* __restrict__ dstArr,
                                                     int* __restrict__ cnt,
                                                     int* __restrict__ csrF) {
    __shared__ u16 Wt[128][WKS];   // 34816 B
    int tid = threadIdx.x;

    if (blockIdx.x < SCATB) {      // ---- scatter role ----
        int gid = blockIdx.x * 512 + tid;
        for (int e = gid; e < ET; e += SCATB * 512) {
            int s, d;
            if (e < N_EDGES) { s = srcArr[e]; d = dstArr[e]; } else { s = d = e - N_EDGES; }
            int pos = atomicAdd(&cnt[d], 1);
            csrF[d * CAP + pos] = s;
        }
        return;
    }

    // ---- gemm role ----
    int bm = (blockIdx.x - SCATB) * 128;

    int w = tid >> 6, lane = tid & 63, l15 = lane & 15, q = lane >> 4;
    int mr = bm + w * 16 + l15;
    if (mr > M - 1) mr = M - 1;

    short8 af[4];
#pragma unroll
    for (int kc = 0; kc < 4; ++kc) {
        const float* ap = x + (size_t)mr * F0 + kc * 32 + q * 8;
        float4 a0 = *(const float4*)ap;
        float4 a1 = *(const float4*)(ap + 4);
        af[kc][0] = (short)f2bf(a0.x); af[kc][1] = (short)f2bf(a0.y);
        af[kc][2] = (short)f2bf(a0.z); af[kc][3] = (short)f2bf(a0.w);
        af[kc][4] = (short)f2bf(a1.x); af[kc][5] = (short)f2bf(a1.y);
        af[kc][6] = (short)f2bf(a1.z); af[kc][7] = (short)f2bf(a1.w);
    }

    f32x4 acc[16];
#pragma unroll
    for (int t = 0; t < 16; ++t) acc[t] = (f32x4){0.f, 0.f, 0.f, 0.f};

#pragma unroll
    for (int half = 0; half < 2; ++half) {
        __syncthreads();
        for (int idx = tid; idx < 128 * F0 / 8; idx += 512) {
            int n = idx >> 4, c = idx & 15;
            *(short8*)&Wt[n][c * 8] =
                *(const short8*)(W1t + (size_t)(half * 128 + n) * F0 + c * 8);
        }
        __syncthreads();
#pragma unroll
        for (int t = 0; t < 8; ++t) {
#pragma unroll
            for (int kc = 0; kc < 4; ++kc) {
                short8 bf = *(const short8*)&Wt[t * 16 + l15][kc * 32 + q * 8];
                acc[half * 8 + t] =
                    __builtin_amdgcn_mfma_f32_16x16x32_bf16(af[kc], bf, acc[half * 8 + t], 0, 0, 0);
            }
        }
    }

#pragma unroll
    for (int r = 0; r < 4; ++r) {
        int row = bm + w * 16 + q * 4 + r;
        if (row >= M) continue;
        size_t base = (size_t)row * D1;
#pragma unroll
        for (int t = 0; t < 16; ++t)
            h1b[base + t * 16 + l15] = f2bf(acc[t][r]);
    }

#pragma unroll
    for (int lh = 0; lh < 8; ++lh) {
        float aS0  = aS1[lh * 32 + l15];
        float aS16 = aS1[lh * 32 + 16 + l15];
        float aD0  = aD1[lh * 32 + l15];
        float aD16 = aD1[lh * 32 + 16 + l15];
#pragma unroll
        for (int r = 0; r < 4; ++r) {
            float s1 = acc[2 * lh][r] * aS0 + acc[2 * lh + 1][r] * aS16;
            float s2 = acc[2 * lh][r] * aD0 + acc[2 * lh + 1][r] * aD16;
            s1 += __shfl_xor(s1, 1); s1 += __shfl_xor(s1, 2);
            s1 += __shfl_xor(s1, 4); s1 += __shfl_xor(s1, 8);
            s2 += __shfl_xor(s2, 1); s2 += __shfl_xor(s2, 2);
            s2 += __shfl_xor(s2, 4); s2 += __shfl_xor(s2, 8);
            int row = bm + w * 16 + q * 4 + r;
            if (l15 == 0 && row < M) {
                as[row * 8 + lh] = s1;
                ad[row * 8 + lh] = s2;
            }
        }
    }
}

// ---------------- gemm2: x2b[M,256](bf16) @ W2t -> h2b bf16 [M,32] + fused alpha ----------------

__global__ __launch_bounds__(256) void gemm2_mfma(const u16* __restrict__ A,
                                                  const u16* __restrict__ W2t,
                                                  const float* __restrict__ aS2,
                                                  const float* __restrict__ aD2,
                                                  u16* __restrict__ h2b,
                                                  float* __restrict__ as,
                                                  float* __restrict__ ad, int M) {
    int tid = threadIdx.x;
    int bm = blockIdx.x * 64;
    int w = tid >> 6, lane = tid & 63, l15 = lane & 15, q = lane >> 4;
    int mr = bm + w * 16 + l15;
    if (mr > M - 1) mr = M - 1;

    f32x4 acc0 = {0.f, 0.f, 0.f, 0.f};
    f32x4 acc1 = {0.f, 0.f, 0.f, 0.f};
    const u16* b0p = W2t + (size_t)(0 * 16 + l15) * D1;
    const u16* b1p = W2t + (size_t)(1 * 16 + l15) * D1;
#pragma unroll
    for (int k0 = 0; k0 < D1; k0 += 32) {
        short8 af = *(const short8*)(A + (size_t)mr * D1 + k0 + q * 8);
        short8 b0 = *(const short8*)(b0p + k0 + q * 8);
        short8 b1 = *(const short8*)(b1p + k0 + q * 8);
        acc0 = __builtin_amdgcn_mfma_f32_16x16x32_bf16(af, b0, acc0, 0, 0, 0);
        acc1 = __builtin_amdgcn_mfma_f32_16x16x32_bf16(af, b1, acc1, 0, 0, 0);
    }

    float aS0 = aS2[l15], aS16 = aS2[16 + l15];
    float aD0 = aD2[l15], aD16 = aD2[16 + l15];
#pragma unroll
    for (int r = 0; r < 4; ++r) {
        int row = bm + w * 16 + q * 4 + r;
        float s1 = acc0[r] * aS0 + acc1[r] * aS16;
        float s2 = acc0[r] * aD0 + acc1[r] * aD16;
        s1 += __shfl_xor(s1, 1); s1 += __shfl_xor(s1, 2);
        s1 += __shfl_xor(s1, 4); s1 += __shfl_xor(s1, 8);
        s2 += __shfl_xor(s2, 1); s2 += __shfl_xor(s2, 2);
        s2 += __shfl_xor(s2, 4); s2 += __shfl_xor(s2, 8);
        if (row < M) {
            h2b[(size_t)row * C2 + 0 * 16 + l15] = f2bf(acc0[r]);
            h2b[(size_t)row * C2 + 1 * 16 + l15] = f2bf(acc1[r]);
            if (l15 == 0) { as[row] = s1; ad[row] = s2; }
        }
    }
}

// ---------------- gemm3: x3b[M,32](bf16) @ W3t -> h3b bf16 [M,64] + fused alpha ----------------

__global__ __launch_bounds__(256) void gemm3_mfma(const u16* __restrict__ A,
                                                  const u16* __restrict__ W3t,
                                                  const float* __restrict__ aS3,
                                                  const float* __restrict__ aD3,
                                                  u16* __restrict__ h3b,
                                                  float* __restrict__ as,
                                                  float* __restrict__ ad, int M) {
    int tid = threadIdx.x;
    int bm = blockIdx.x * 64;
    int w = tid >> 6, lane = tid & 63, l15 = lane & 15, q = lane >> 4;
    int mr = bm + w * 16 + l15;
    if (mr > M - 1) mr = M - 1;

    short8 af = *(const short8*)(A + (size_t)mr * C2 + q * 8);

    f32x4 acc[4];
#pragma unroll
    for (int t = 0; t < 4; ++t) {
        short8 bf = *(const short8*)(W3t + (size_t)(t * 16 + l15) * C2 + q * 8);
        f32x4 z = {0.f, 0.f, 0.f, 0.f};
        acc[t] = __builtin_amdgcn_mfma_f32_16x16x32_bf16(af, bf, z, 0, 0, 0);
    }

    float aSv[4], aDv[4];
#pragma unroll
    for (int t = 0; t < 4; ++t) {
        aSv[t] = aS3[t * 16 + l15];
        aDv[t] = aD3[t * 16 + l15];
    }
#pragma unroll
    for (int r = 0; r < 4; ++r) {
        int row = bm + w * 16 + q * 4 + r;
        float s1 = acc[0][r] * aSv[0] + acc[1][r] * aSv[1] + acc[2][r] * aSv[2] + acc[3][r] * aSv[3];
        float s2 = acc[0][r] * aDv[0] + acc[1][r] * aDv[1] + acc[2][r] * aDv[2] + acc[3][r] * aDv[3];
        s1 += __shfl_xor(s1, 1); s1 += __shfl_xor(s1, 2);
        s1 += __shfl_xor(s1, 4); s1 += __shfl_xor(s1, 8);
        s2 += __shfl_xor(s2, 1); s2 += __shfl_xor(s2, 2);
        s2 += __shfl_xor(s2, 4); s2 += __shfl_xor(s2, 8);
        if (row < M) {
            size_t base = (size_t)row * C3;
#pragma unroll
            for (int t = 0; t < 4; ++t)
                h3b[base + t * 16 + l15] = f2bf(acc[t][r]);
            if (l15 == 0) { as[row] = s1; ad[row] = s2; }
        }
    }
}

// ---------------- layer 1 aggregation: H=8, C=32, wave per node (66.7us plateau structure) ----------------

__global__ __launch_bounds__(256) void agg1_kernel(const int* __restrict__ cnt, const int* __restrict__ csrF,
                                                   const u16* __restrict__ h, const float* __restrict__ as,
                                                   const float* __restrict__ ad, const float* __restrict__ bias,
                                                   u16* __restrict__ outb) {
    int node = blockIdx.x * 4 + (threadIdx.x >> 6);
    if (node >= N_NODES) return;
    int lane = threadIdx.x & 63;
    int hh = lane >> 3;   // accumulate: head     | w-table: slot-in-group
    int j  = lane & 7;    // accumulate: chan grp | w-table: head
    int s0 = node * CAP;
    int deg = cnt[node];
    int dmain = deg < 64 ? deg : 64;
    int idxv = (lane < dmain) ? csrF[s0 + lane] : 0;
    float adw = ad[node * H1 + j];
    const u16* hb = h + hh * C1 + j * 4;

    // ---- weight table: slot indices, then 8 gathers back-to-back, then exps ----
    int sAll[8];
#pragma unroll
    for (int r = 0; r < 8; ++r) sAll[r] = __shfl(idxv, r * 8 + hh);
    float aAll[8];
#pragma unroll
    for (int r = 0; r < 8; ++r) aAll[r] = as[sAll[r] * H1 + j];
    float wAll[8];
#pragma unroll
    for (int r = 0; r < 8; ++r)
        wAll[r] = (r * 8 + hh < dmain) ? __expf(lrelu(aAll[r] + adw)) : 0.f;

    // denominator: per-lane partial over slot groups, reduce across lane>>3
    float ws = wAll[0] + wAll[1] + wAll[2] + wAll[3]
             + wAll[4] + wAll[5] + wAll[6] + wAll[7];
    ws += __shfl_xor(ws, 8);
    ws += __shfl_xor(ws, 16);
    ws += __shfl_xor(ws, 32);
    float dsum = __shfl(ws, hh);   // lane hh (lane&7==hh) holds total for head hh

    // ---- main loop: pure shfl + gather + fma ----
    float4 acc = make_float4(0.f, 0.f, 0.f, 0.f);
    for (int base = 0; base < dmain; base += 8) {
        int r = base >> 3;
        int su[8];
#pragma unroll
        for (int u = 0; u < 8; ++u) su[u] = __shfl(idxv, base + u);
        uint2 v[8];
#pragma unroll
        for (int u = 0; u < 8; ++u) v[u] = *(const uint2*)(hb + (size_t)su[u] * D1);
        float wr = wAll[0];
#pragma unroll
        for (int t = 1; t < 8; ++t) if (t == r) wr = wAll[t];   // static-index select
#pragma unroll
        for (int u = 0; u < 8; ++u) {
            float wv = __shfl(wr, u * 8 + hh);
            float4 hv = bf4_to_f4(v[u]);
            acc.x += wv * hv.x; acc.y += wv * hv.y;
            acc.z += wv * hv.z; acc.w += wv * hv.w;
        }
    }

    for (int i = 64; i < deg; ++i) {          // deg > 64 fallback (never taken for this input)
        int s = csrF[s0 + i];
        float4 hv = bf4_to_f4(*(const uint2*)(hb + (size_t)s * D1));
        float w = __expf(lrelu(as[s * H1 + hh] + ad[node * H1 + hh]));
        dsum += w;
        acc.x += w * hv.x; acc.y += w * hv.y; acc.z += w * hv.z; acc.w += w * hv.w;
    }

    float inv = 1.f / (dsum + 1e-16f);
    int ob = node * D1 + hh * C1 + j * 4;
    const float* bp = bias + hh * C1 + j * 4;
    float rx = eluf(acc.x * inv + bp[0]);
    float ry = eluf(acc.y * inv + bp[1]);
    float rz = eluf(acc.z * inv + bp[2]);
    float rw = eluf(acc.w * inv + bp[3]);
    uint2 pr;
    pr.x = pack2bf(rx, ry);
    pr.y = pack2bf(rz, rw);
    *(uint2*)(outb + ob) = pr;
}

// ---------------- layer 2 aggregation: C=32, uniform predicated rounds (16 edges/round) ----------------

__global__ __launch_bounds__(256) void agg32_kernel(const int* __restrict__ cnt, const int* __restrict__ csrF,
                                                    const u16* __restrict__ h, const float* __restrict__ as,
                                                    const float* __restrict__ ad, const float* __restrict__ bias,
                                                    u16* __restrict__ outb) {
    int node = blockIdx.x * 4 + (threadIdx.x >> 6);
    if (node >= N_NODES) return;
    int lane = threadIdx.x & 63;
    int eg = lane >> 3;     // 0..7
    int cg = lane & 7;
    int s0 = node * CAP;
    int deg = cnt[node];
    int dmain = deg < 64 ? deg : 64;
    int idxv = (lane < dmain) ? csrF[s0 + lane] : 0;
    float adv = ad[node];

    float4 acc = make_float4(0.f, 0.f, 0.f, 0.f);
    float dsum = 0.f;
    for (int base = 0; base < dmain; base += 16) {    // uniform rounds, all lanes active
        int i0 = base + eg;
        int i1 = base + eg + 8;
        int sa = __shfl(idxv, i0);
        int sb = __shfl(idxv, i1);
        uint2 va = *(const uint2*)(h + (size_t)sa * C2 + cg * 4);
        uint2 vb = *(const uint2*)(h + (size_t)sb * C2 + cg * 4);
        float wa = (i0 < dmain) ? __expf(lrelu(as[sa] + adv)) : 0.f;
        float wb = (i1 < dmain) ? __expf(lrelu(as[sb] + adv)) : 0.f;
        float4 ha = bf4_to_f4(va);
        float4 hb = bf4_to_f4(vb);
        dsum += wa + wb;
        acc.x += wa * ha.x + wb * hb.x;
        acc.y += wa * ha.y + wb * hb.y;
        acc.z += wa * ha.z + wb * hb.z;
        acc.w += wa * ha.w + wb * hb.w;
    }
    for (int i = 64 + eg; i < deg; i += 8) {          // deg > 64 fallback
        int s = csrF[s0 + i];
        float4 hv = bf4_to_f4(*(const uint2*)(h + (size_t)s * C2 + cg * 4));
        float w = __expf(lrelu(as[s] + adv));
        dsum += w;
        acc.x += w * hv.x; acc.y += w * hv.y; acc.z += w * hv.z; acc.w += w * hv.w;
    }
#pragma unroll
    for (int o = 8; o < 64; o <<= 1) {
        acc.x += __shfl_xor(acc.x, o);
        acc.y += __shfl_xor(acc.y, o);
        acc.z += __shfl_xor(acc.z, o);
        acc.w += __shfl_xor(acc.w, o);
        dsum  += __shfl_xor(dsum, o);
    }
    if (eg == 0) {
        float inv = 1.f / (dsum + 1e-16f);
        const float* bp = bias + cg * 4;
        float rx = eluf(acc.x * inv + bp[0]);
        float ry = eluf(acc.y * inv + bp[1]);
        float rz = eluf(acc.z * inv + bp[2]);
        float rw = eluf(acc.w * inv + bp[3]);
        uint2 pr;
        pr.x = pack2bf(rx, ry);
        pr.y = pack2bf(rz, rw);
        *(uint2*)(outb + (size_t)node * C2 + cg * 4) = pr;
    }
}

// ---------------- layer 3 aggregation: C=64, uniform predicated rounds (8 edges/round), f32 out ----------------

__global__ __launch_bounds__(256) void agg64_kernel(const int* __restrict__ cnt, const int* __restrict__ csrF,
                                                    const u16* __restrict__ h, const float* __restrict__ as,
                                                    const float* __restrict__ ad, const float* __restrict__ bias,
                                                    float* __restrict__ out) {
    int node = blockIdx.x * 4 + (threadIdx.x >> 6);
    if (node >= N_NODES) return;
    int lane = threadIdx.x & 63;
    int eg = lane >> 4;     // 0..3
    int cg = lane & 15;
    int s0 = node * CAP;
    int deg = cnt[node];
    int dmain = deg < 64 ? deg : 64;
    int idxv = (lane < dmain) ? csrF[s0 + lane] : 0;
    float adv = ad[node];

    float4 acc = make_float4(0.f, 0.f, 0.f, 0.f);
    float dsum = 0.f;
    for (int base = 0; base < dmain; base += 8) {     // uniform rounds, all lanes active
        int i0 = base + eg;
        int i1 = base + eg + 4;
        int sa = __shfl(idxv, i0);
        int sb = __shfl(idxv, i1);
        uint2 va = *(const uint2*)(h + (size_t)sa * C3 + cg * 4);
        uint2 vb = *(const uint2*)(h + (size_t)sb * C3 + cg * 4);
        float wa = (i0 < dmain) ? __expf(lrelu(as[sa] + adv)) : 0.f;
        float wb = (i1 < dmain) ? __expf(lrelu(as[sb] + adv)) : 0.f;
        float4 ha = bf4_to_f4(va);
        float4 hb = bf4_to_f4(vb);
        dsum += wa + wb;
        acc.x += wa * ha.x + wb * hb.x;
        acc.y += wa * ha.y + wb * hb.y;
        acc.z += wa * ha.z + wb * hb.z;
        acc.w += wa * ha.w + wb * hb.w;
    }
    for (int i = 64 + eg; i < deg; i += 4) {          // deg > 64 fallback
        int s = csrF[s0 + i];
        float4 hv = bf4_to_f4(*(const uint2*)(h + (size_t)s * C3 + cg * 4));
        float w = __expf(lrelu(as[s] + adv));
        dsum += w;
        acc.x += w * hv.x; acc.y += w * hv.y; acc.z += w * hv.z; acc.w += w * hv.w;
    }
#pragma unroll
    for (int o = 16; o < 64; o <<= 1) {
        acc.x += __shfl_xor(acc.x, o);
        acc.y += __shfl_xor(acc.y, o);
        acc.z += __shfl_xor(acc.z, o);
        acc.w += __shfl_xor(acc.w, o);
        dsum  += __shfl_xor(dsum, o);
    }
    if (eg == 0) {
        float inv = 1.f / (dsum + 1e-16f);
        const float* bp = bias + cg * 4;
        float4 r;
        r.x = acc.x * inv + bp[0];
        r.y = acc.y * inv + bp[1];
        r.z = acc.z * inv + bp[2];
        r.w = acc.w * inv + bp[3];
        *(float4*)(out + (size_t)node * C3 + cg * 4) = r;
    }
}

// ---------------- launch ----------------

extern "C" void kernel_launch(void* const* d_in, const int* in_sizes, int n_in,
                              void* d_out, int out_size, void* d_ws, size_t ws_size,
                              hipStream_t stream) {
    const float* x   = (const float*)d_in[0];
    const int*   ei  = (const int*)d_in[1];
    const float* W1  = (const float*)d_in[2];
    const float* aS1 = (const float*)d_in[3];
    const float* aD1 = (const float*)d_in[4];
    const float* b1  = (const float*)d_in[5];
    const float* W2  = (const float*)d_in[6];
    const float* aS2 = (const float*)d_in[7];
    const float* aD2 = (const float*)d_in[8];
    const float* b2  = (const float*)d_in[9];
    const float* W3  = (const float*)d_in[10];
    const float* aS3 = (const float*)d_in[11];
    const float* aD3 = (const float*)d_in[12];
    const float* b3  = (const float*)d_in[13];
    float* out = (float*)d_out;

    char* p = (char*)d_ws;
    auto alloc = [&](size_t bytes) -> void* {
        void* r = (void*)p;
        p += (bytes + 255) & ~(size_t)255;
        return r;
    };
    u16*   h1b  = (u16*)alloc((size_t)N_NODES * D1 * 2);
    u16*   x2b  = (u16*)alloc((size_t)N_NODES * D1 * 2);
    u16*   h2b  = (u16*)alloc((size_t)N_NODES * C2 * 2);
    u16*   x3b  = (u16*)alloc((size_t)N_NODES * C2 * 2);
    u16*   h3b  = (u16*)alloc((size_t)N_NODES * C3 * 2);
    int*   cnt  = (int*)alloc((size_t)N_NODES * 4);
    int*   csrF = (int*)alloc((size_t)N_NODES * CAP * 4);
    float* asb  = (float*)alloc((size_t)N_NODES * H1 * 4);
    float* adb  = (float*)alloc((size_t)N_NODES * H1 * 4);
    u16*   W1t  = (u16*)alloc((size_t)F0 * D1 * 2);
    u16*   W2t  = (u16*)alloc((size_t)D1 * C2 * 2);
    u16*   W3t  = (u16*)alloc((size_t)C2 * C3 * 2);

    const int* srcArr = ei;
    const int* dstArr = ei + N_EDGES;

    prep_kernel<<<(N_NODES + 255) / 256, 256, 0, stream>>>(W1, W2, W3, W1t, W2t, W3t, cnt);

    int nb4 = (N_NODES + 3) / 4;
    int mb64 = (N_NODES + 63) / 64;
    int mb128 = (N_NODES + 127) / 128;

    // layer 1 gemm with fused edge scatter (scatter blocks first, then gemm blocks)
    gemm1_scat<<<SCATB + mb128, 512, 0, stream>>>(W1t, x, aS1, aD1, h1b, asb, adb, N_NODES,
                                                  srcArr, dstArr, cnt, csrF);
    agg1_kernel<<<nb4, 256, 0, stream>>>(cnt, csrF, h1b, asb, adb, b1, x2b);

    gemm2_mfma<<<mb64, 256, 0, stream>>>(x2b, W2t, aS2, aD2, h2b, asb, adb, N_NODES);
    agg32_kernel<<<nb4, 256, 0, stream>>>(cnt, csrF, h2b, asb, adb, b2, x3b);

    gemm3_mfma<<<mb64, 256, 0, stream>>>(x3b, W3t, aS3, aD3, h3b, asb, adb, N_NODES);
    agg64_kernel<<<nb4, 256, 0, stream>>>(cnt, csrF, h3b, asb, adb, b3, out);
}

// Round 12
// 295.667 us; speedup vs baseline: 1.0840x; 1.0840x over previous
//
#include <hip/hip_runtime.h>
#include <hip/hip_bf16.h>
#include <math.h>

#define N_NODES 50000
#define N_EDGES 800000
#define ET (N_EDGES + N_NODES)   // with self loops = 850000
#define F0 128
#define H1 8
#define C1 32
#define D1 (H1*C1)               // 256
#define C2 32
#define C3 64
#define CAP 128                   // fixed bucket capacity (max deg ~45 for this input; 128 = huge margin)
#define GEMMB 391                 // gemm-role blocks (ceil(50000/128)) -- dispatched FIRST
#define SCATB 1661                // scatter-role blocks after (ceil(ET/512)), 1 edge/thread

typedef unsigned short u16;
typedef unsigned int u32;
typedef __attribute__((ext_vector_type(8))) short short8;
typedef __attribute__((ext_vector_type(4))) float f32x4;

__device__ __forceinline__ float lrelu(float x) { return x >= 0.f ? x : 0.2f * x; }
__device__ __forceinline__ float eluf(float x)  { return x > 0.f ? x : (expf(x) - 1.f); }

__device__ __forceinline__ u16 f2bf(float f) {
    u32 u = __float_as_uint(f);
    return (u16)((u + 0x7FFFu + ((u >> 16) & 1u)) >> 16);   // RNE
}
__device__ __forceinline__ u32 pack2bf(float lo, float hi) {
    return ((u32)f2bf(hi) << 16) | (u32)f2bf(lo);
}
__device__ __forceinline__ float4 bf4_to_f4(uint2 v) {
    float4 r;
    r.x = __uint_as_float(v.x << 16);
    r.y = __uint_as_float(v.x & 0xFFFF0000u);
    r.z = __uint_as_float(v.y << 16);
    r.w = __uint_as_float(v.y & 0xFFFF0000u);
    return r;
}

// ---------------- prep: zero cnt + weight transposes/conversions (one kernel, no deps) ----------------

__global__ void prep_kernel(const float* __restrict__ W1, const float* __restrict__ W2,
                            const float* __restrict__ W3,
                            u16* __restrict__ W1t, u16* __restrict__ W2t, u16* __restrict__ W3t,
                            int* __restrict__ cnt) {
    int t = blockIdx.x * 256 + threadIdx.x;
    if (t < N_NODES) cnt[t] = 0;
    if (t < F0 * D1) {            // W1[128][256] -> W1t[256][128] bf16 (n-major, coalesced writes)
        int n = t >> 7, k = t & 127;
        W1t[n * F0 + k] = f2bf(W1[(size_t)k * D1 + n]);
    }
    if (t < D1 * C2) {            // W2[256][32] -> W2t[32][256]
        int k = t >> 5, n = t & 31;
        W2t[n * D1 + k] = f2bf(W2[t]);
    }
    if (t < C2 * C3) {            // W3[32][64] -> W3t[64][32]
        int k = t >> 6, n = t & 63;
        W3t[n * C2 + k] = f2bf(W3[t]);
    }
}

// ---------------- gemm1 + fused edge scatter (block-role split, v2) ----------------
// v2 fixes from R11 counters: (1) gemm blocks FIRST in grid so CUs fill with MFMA work
// and the atomic drain runs underneath/after; (2) scatter role is 1 edge per thread
// (R6's proven shape) -- no grid-stride dependent atomic chains.

#define WKS 136

__global__ __launch_bounds__(512, 2) void gemm1_scat(const u16* __restrict__ W1t,
                                                     const float* __restrict__ x,
                                                     const float* __restrict__ aS1,
                                                     const float* __restrict__ aD1,
                                                     u16* __restrict__ h1b,
                                                     float* __restrict__ as,
                                                     float* __restrict__ ad, int M,
                                                     const int* __restrict__ srcArr,
                                                     const int* __restrict__ dstArr,
                                                     int* __restrict__ cnt,
                                                     int* __restrict__ csrF) {
    __shared__ u16 Wt[128][WKS];   // 34816 B
    int tid = threadIdx.x;

    if (blockIdx.x >= GEMMB) {     // ---- scatter role: exactly one edge per thread ----
        int e = (blockIdx.x - GEMMB) * 512 + tid;
        if (e < ET) {
            int s, d;
            if (e < N_EDGES) { s = srcArr[e]; d = dstArr[e]; } else { s = d = e - N_EDGES; }
            int pos = atomicAdd(&cnt[d], 1);
            csrF[d * CAP + pos] = s;
        }
        return;
    }

    // ---- gemm role ----
    int bm = blockIdx.x * 128;

    int w = tid >> 6, lane = tid & 63, l15 = lane & 15, q = lane >> 4;
    int mr = bm + w * 16 + l15;
    if (mr > M - 1) mr = M - 1;

    short8 af[4];
#pragma unroll
    for (int kc = 0; kc < 4; ++kc) {
        const float* ap = x + (size_t)mr * F0 + kc * 32 + q * 8;
        float4 a0 = *(const float4*)ap;
        float4 a1 = *(const float4*)(ap + 4);
        af[kc][0] = (short)f2bf(a0.x); af[kc][1] = (short)f2bf(a0.y);
        af[kc][2] = (short)f2bf(a0.z); af[kc][3] = (short)f2bf(a0.w);
        af[kc][4] = (short)f2bf(a1.x); af[kc][5] = (short)f2bf(a1.y);
        af[kc][6] = (short)f2bf(a1.z); af[kc][7] = (short)f2bf(a1.w);
    }

    f32x4 acc[16];
#pragma unroll
    for (int t = 0; t < 16; ++t) acc[t] = (f32x4){0.f, 0.f, 0.f, 0.f};

#pragma unroll
    for (int half = 0; half < 2; ++half) {
        __syncthreads();
        for (int idx = tid; idx < 128 * F0 / 8; idx += 512) {
            int n = idx >> 4, c = idx & 15;
            *(short8*)&Wt[n][c * 8] =
                *(const short8*)(W1t + (size_t)(half * 128 + n) * F0 + c * 8);
        }
        __syncthreads();
#pragma unroll
        for (int t = 0; t < 8; ++t) {
#pragma unroll
            for (int kc = 0; kc < 4; ++kc) {
                short8 bf = *(const short8*)&Wt[t * 16 + l15][kc * 32 + q * 8];
                acc[half * 8 + t] =
                    __builtin_amdgcn_mfma_f32_16x16x32_bf16(af[kc], bf, acc[half * 8 + t], 0, 0, 0);
            }
        }
    }

#pragma unroll
    for (int r = 0; r < 4; ++r) {
        int row = bm + w * 16 + q * 4 + r;
        if (row >= M) continue;
        size_t base = (size_t)row * D1;
#pragma unroll
        for (int t = 0; t < 16; ++t)
            h1b[base + t * 16 + l15] = f2bf(acc[t][r]);
    }

#pragma unroll
    for (int lh = 0; lh < 8; ++lh) {
        float aS0  = aS1[lh * 32 + l15];
        float aS16 = aS1[lh * 32 + 16 + l15];
        float aD0  = aD1[lh * 32 + l15];
        float aD16 = aD1[lh * 32 + 16 + l15];
#pragma unroll
        for (int r = 0; r < 4; ++r) {
            float s1 = acc[2 * lh][r] * aS0 + acc[2 * lh + 1][r] * aS16;
            float s2 = acc[2 * lh][r] * aD0 + acc[2 * lh + 1][r] * aD16;
            s1 += __shfl_xor(s1, 1); s1 += __shfl_xor(s1, 2);
            s1 += __shfl_xor(s1, 4); s1 += __shfl_xor(s1, 8);
            s2 += __shfl_xor(s2, 1); s2 += __shfl_xor(s2, 2);
            s2 += __shfl_xor(s2, 4); s2 += __shfl_xor(s2, 8);
            int row = bm + w * 16 + q * 4 + r;
            if (l15 == 0 && row < M) {
                as[row * 8 + lh] = s1;
                ad[row * 8 + lh] = s2;
            }
        }
    }
}

// ---------------- gemm2: x2b[M,256](bf16) @ W2t -> h2b bf16 [M,32] + fused alpha ----------------

__global__ __launch_bounds__(256) void gemm2_mfma(const u16* __restrict__ A,
                                                  const u16* __restrict__ W2t,
                                                  const float* __restrict__ aS2,
                                                  const float* __restrict__ aD2,
                                                  u16* __restrict__ h2b,
                                                  float* __restrict__ as,
                                                  float* __restrict__ ad, int M) {
    int tid = threadIdx.x;
    int bm = blockIdx.x * 64;
    int w = tid >> 6, lane = tid & 63, l15 = lane & 15, q = lane >> 4;
    int mr = bm + w * 16 + l15;
    if (mr > M - 1) mr = M - 1;

    f32x4 acc0 = {0.f, 0.f, 0.f, 0.f};
    f32x4 acc1 = {0.f, 0.f, 0.f, 0.f};
    const u16* b0p = W2t + (size_t)(0 * 16 + l15) * D1;
    const u16* b1p = W2t + (size_t)(1 * 16 + l15) * D1;
#pragma unroll
    for (int k0 = 0; k0 < D1; k0 += 32) {
        short8 af = *(const short8*)(A + (size_t)mr * D1 + k0 + q * 8);
        short8 b0 = *(const short8*)(b0p + k0 + q * 8);
        short8 b1 = *(const short8*)(b1p + k0 + q * 8);
        acc0 = __builtin_amdgcn_mfma_f32_16x16x32_bf16(af, b0, acc0, 0, 0, 0);
        acc1 = __builtin_amdgcn_mfma_f32_16x16x32_bf16(af, b1, acc1, 0, 0, 0);
    }

    float aS0 = aS2[l15], aS16 = aS2[16 + l15];
    float aD0 = aD2[l15], aD16 = aD2[16 + l15];
#pragma unroll
    for (int r = 0; r < 4; ++r) {
        int row = bm + w * 16 + q * 4 + r;
        float s1 = acc0[r] * aS0 + acc1[r] * aS16;
        float s2 = acc0[r] * aD0 + acc1[r] * aD16;
        s1 += __shfl_xor(s1, 1); s1 += __shfl_xor(s1, 2);
        s1 += __shfl_xor(s1, 4); s1 += __shfl_xor(s1, 8);
        s2 += __shfl_xor(s2, 1); s2 += __shfl_xor(s2, 2);
        s2 += __shfl_xor(s2, 4); s2 += __shfl_xor(s2, 8);
        if (row < M) {
            h2b[(size_t)row * C2 + 0 * 16 + l15] = f2bf(acc0[r]);
            h2b[(size_t)row * C2 + 1 * 16 + l15] = f2bf(acc1[r]);
            if (l15 == 0) { as[row] = s1; ad[row] = s2; }
        }
    }
}

// ---------------- gemm3: x3b[M,32](bf16) @ W3t -> h3b bf16 [M,64] + fused alpha ----------------

__global__ __launch_bounds__(256) void gemm3_mfma(const u16* __restrict__ A,
                                                  const u16* __restrict__ W3t,
                                                  const float* __restrict__ aS3,
                                                  const float* __restrict__ aD3,
                                                  u16* __restrict__ h3b,
                                                  float* __restrict__ as,
                                                  float* __restrict__ ad, int M) {
    int tid = threadIdx.x;
    int bm = blockIdx.x * 64;
    int w = tid >> 6, lane = tid & 63, l15 = lane & 15, q = lane >> 4;
    int mr = bm + w * 16 + l15;
    if (mr > M - 1) mr = M - 1;

    short8 af = *(const short8*)(A + (size_t)mr * C2 + q * 8);

    f32x4 acc[4];
#pragma unroll
    for (int t = 0; t < 4; ++t) {
        short8 bf = *(const short8*)(W3t + (size_t)(t * 16 + l15) * C2 + q * 8);
        f32x4 z = {0.f, 0.f, 0.f, 0.f};
        acc[t] = __builtin_amdgcn_mfma_f32_16x16x32_bf16(af, bf, z, 0, 0, 0);
    }

    float aSv[4], aDv[4];
#pragma unroll
    for (int t = 0; t < 4; ++t) {
        aSv[t] = aS3[t * 16 + l15];
        aDv[t] = aD3[t * 16 + l15];
    }
#pragma unroll
    for (int r = 0; r < 4; ++r) {
        int row = bm + w * 16 + q * 4 + r;
        float s1 = acc[0][r] * aSv[0] + acc[1][r] * aSv[1] + acc[2][r] * aSv[2] + acc[3][r] * aSv[3];
        float s2 = acc[0][r] * aDv[0] + acc[1][r] * aDv[1] + acc[2][r] * aDv[2] + acc[3][r] * aDv[3];
        s1 += __shfl_xor(s1, 1); s1 += __shfl_xor(s1, 2);
        s1 += __shfl_xor(s1, 4); s1 += __shfl_xor(s1, 8);
        s2 += __shfl_xor(s2, 1); s2 += __shfl_xor(s2, 2);
        s2 += __shfl_xor(s2, 4); s2 += __shfl_xor(s2, 8);
        if (row < M) {
            size_t base = (size_t)row * C3;
#pragma unroll
            for (int t = 0; t < 4; ++t)
                h3b[base + t * 16 + l15] = f2bf(acc[t][r]);
            if (l15 == 0) { as[row] = s1; ad[row] = s2; }
        }
    }
}

// ---------------- layer 1 aggregation: H=8, C=32, wave per node (66.7us plateau structure) ----------------

__global__ __launch_bounds__(256) void agg1_kernel(const int* __restrict__ cnt, const int* __restrict__ csrF,
                                                   const u16* __restrict__ h, const float* __restrict__ as,
                                                   const float* __restrict__ ad, const float* __restrict__ bias,
                                                   u16* __restrict__ outb) {
    int node = blockIdx.x * 4 + (threadIdx.x >> 6);
    if (node >= N_NODES) return;
    int lane = threadIdx.x & 63;
    int hh = lane >> 3;   // accumulate: head     | w-table: slot-in-group
    int j  = lane & 7;    // accumulate: chan grp | w-table: head
    int s0 = node * CAP;
    int deg = cnt[node];
    int dmain = deg < 64 ? deg : 64;
    int idxv = (lane < dmain) ? csrF[s0 + lane] : 0;
    float adw = ad[node * H1 + j];
    const u16* hb = h + hh * C1 + j * 4;

    // ---- weight table: slot indices, then 8 gathers back-to-back, then exps ----
    int sAll[8];
#pragma unroll
    for (int r = 0; r < 8; ++r) sAll[r] = __shfl(idxv, r * 8 + hh);
    float aAll[8];
#pragma unroll
    for (int r = 0; r < 8; ++r) aAll[r] = as[sAll[r] * H1 + j];
    float wAll[8];
#pragma unroll
    for (int r = 0; r < 8; ++r)
        wAll[r] = (r * 8 + hh < dmain) ? __expf(lrelu(aAll[r] + adw)) : 0.f;

    // denominator: per-lane partial over slot groups, reduce across lane>>3
    float ws = wAll[0] + wAll[1] + wAll[2] + wAll[3]
             + wAll[4] + wAll[5] + wAll[6] + wAll[7];
    ws += __shfl_xor(ws, 8);
    ws += __shfl_xor(ws, 16);
    ws += __shfl_xor(ws, 32);
    float dsum = __shfl(ws, hh);   // lane hh (lane&7==hh) holds total for head hh

    // ---- main loop: pure shfl + gather + fma ----
    float4 acc = make_float4(0.f, 0.f, 0.f, 0.f);
    for (int base = 0; base < dmain; base += 8) {
        int r = base >> 3;
        int su[8];
#pragma unroll
        for (int u = 0; u < 8; ++u) su[u] = __shfl(idxv, base + u);
        uint2 v[8];
#pragma unroll
        for (int u = 0; u < 8; ++u) v[u] = *(const uint2*)(hb + (size_t)su[u] * D1);
        float wr = wAll[0];
#pragma unroll
        for (int t = 1; t < 8; ++t) if (t == r) wr = wAll[t];   // static-index select
#pragma unroll
        for (int u = 0; u < 8; ++u) {
            float wv = __shfl(wr, u * 8 + hh);
            float4 hv = bf4_to_f4(v[u]);
            acc.x += wv * hv.x; acc.y += wv * hv.y;
            acc.z += wv * hv.z; acc.w += wv * hv.w;
        }
    }

    for (int i = 64; i < deg; ++i) {          // deg > 64 fallback (never taken for this input)
        int s = csrF[s0 + i];
        float4 hv = bf4_to_f4(*(const uint2*)(hb + (size_t)s * D1));
        float w = __expf(lrelu(as[s * H1 + hh] + ad[node * H1 + hh]));
        dsum += w;
        acc.x += w * hv.x; acc.y += w * hv.y; acc.z += w * hv.z; acc.w += w * hv.w;
    }

    float inv = 1.f / (dsum + 1e-16f);
    int ob = node * D1 + hh * C1 + j * 4;
    const float* bp = bias + hh * C1 + j * 4;
    float rx = eluf(acc.x * inv + bp[0]);
    float ry = eluf(acc.y * inv + bp[1]);
    float rz = eluf(acc.z * inv + bp[2]);
    float rw = eluf(acc.w * inv + bp[3]);
    uint2 pr;
    pr.x = pack2bf(rx, ry);
    pr.y = pack2bf(rz, rw);
    *(uint2*)(outb + ob) = pr;
}

// ---------------- layer 2 aggregation: C=32, uniform predicated rounds (16 edges/round) ----------------

__global__ __launch_bounds__(256) void agg32_kernel(const int* __restrict__ cnt, const int* __restrict__ csrF,
                                                    const u16* __restrict__ h, const float* __restrict__ as,
                                                    const float* __restrict__ ad, const float* __restrict__ bias,
                                                    u16* __restrict__ outb) {
    int node = blockIdx.x * 4 + (threadIdx.x >> 6);
    if (node >= N_NODES) return;
    int lane = threadIdx.x & 63;
    int eg = lane >> 3;     // 0..7
    int cg = lane & 7;
    int s0 = node * CAP;
    int deg = cnt[node];
    int dmain = deg < 64 ? deg : 64;
    int idxv = (lane < dmain) ? csrF[s0 + lane] : 0;
    float adv = ad[node];

    float4 acc = make_float4(0.f, 0.f, 0.f, 0.f);
    float dsum = 0.f;
    for (int base = 0; base < dmain; base += 16) {    // uniform rounds, all lanes active
        int i0 = base + eg;
        int i1 = base + eg + 8;
        int sa = __shfl(idxv, i0);
        int sb = __shfl(idxv, i1);
        uint2 va = *(const uint2*)(h + (size_t)sa * C2 + cg * 4);
        uint2 vb = *(const uint2*)(h + (size_t)sb * C2 + cg * 4);
        float wa = (i0 < dmain) ? __expf(lrelu(as[sa] + adv)) : 0.f;
        float wb = (i1 < dmain) ? __expf(lrelu(as[sb] + adv)) : 0.f;
        float4 ha = bf4_to_f4(va);
        float4 hb = bf4_to_f4(vb);
        dsum += wa + wb;
        acc.x += wa * ha.x + wb * hb.x;
        acc.y += wa * ha.y + wb * hb.y;
        acc.z += wa * ha.z + wb * hb.z;
        acc.w += wa * ha.w + wb * hb.w;
    }
    for (int i = 64 + eg; i < deg; i += 8) {          // deg > 64 fallback
        int s = csrF[s0 + i];
        float4 hv = bf4_to_f4(*(const uint2*)(h + (size_t)s * C2 + cg * 4));
        float w = __expf(lrelu(as[s] + adv));
        dsum += w;
        acc.x += w * hv.x; acc.y += w * hv.y; acc.z += w * hv.z; acc.w += w * hv.w;
    }
#pragma unroll
    for (int o = 8; o < 64; o <<= 1) {
        acc.x += __shfl_xor(acc.x, o);
        acc.y += __shfl_xor(acc.y, o);
        acc.z += __shfl_xor(acc.z, o);
        acc.w += __shfl_xor(acc.w, o);
        dsum  += __shfl_xor(dsum, o);
    }
    if (eg == 0) {
        float inv = 1.f / (dsum + 1e-16f);
        const float* bp = bias + cg * 4;
        float rx = eluf(acc.x * inv + bp[0]);
        float ry = eluf(acc.y * inv + bp[1]);
        float rz = eluf(acc.z * inv + bp[2]);
        float rw = eluf(acc.w * inv + bp[3]);
        uint2 pr;
        pr.x = pack2bf(rx, ry);
        pr.y = pack2bf(rz, rw);
        *(uint2*)(outb + (size_t)node * C2 + cg * 4) = pr;
    }
}

// ---------------- layer 3 aggregation: C=64, uniform predicated rounds (8 edges/round), f32 out ----------------

__global__ __launch_bounds__(256) void agg64_kernel(const int* __restrict__ cnt, const int* __restrict__ csrF,
                                                    const u16* __restrict__ h, const float* __restrict__ as,
                                                    const float* __restrict__ ad, const float* __restrict__ bias,
                                                    float* __restrict__ out) {
    int node = blockIdx.x * 4 + (threadIdx.x >> 6);
    if (node >= N_NODES) return;
    int lane = threadIdx.x & 63;
    int eg = lane >> 4;     // 0..3
    int cg = lane & 15;
    int s0 = node * CAP;
    int deg = cnt[node];
    int dmain = deg < 64 ? deg : 64;
    int idxv = (lane < dmain) ? csrF[s0 + lane] : 0;
    float adv = ad[node];

    float4 acc = make_float4(0.f, 0.f, 0.f, 0.f);
    float dsum = 0.f;
    for (int base = 0; base < dmain; base += 8) {     // uniform rounds, all lanes active
        int i0 = base + eg;
        int i1 = base + eg + 4;
        int sa = __shfl(idxv, i0);
        int sb = __shfl(idxv, i1);
        uint2 va = *(const uint2*)(h + (size_t)sa * C3 + cg * 4);
        uint2 vb = *(const uint2*)(h + (size_t)sb * C3 + cg * 4);
        float wa = (i0 < dmain) ? __expf(lrelu(as[sa] + adv)) : 0.f;
        float wb = (i1 < dmain) ? __expf(lrelu(as[sb] + adv)) : 0.f;
        float4 ha = bf4_to_f4(va);
        float4 hb = bf4_to_f4(vb);
        dsum += wa + wb;
        acc.x += wa * ha.x + wb * hb.x;
        acc.y += wa * ha.y + wb * hb.y;
        acc.z += wa * ha.z + wb * hb.z;
        acc.w += wa * ha.w + wb * hb.w;
    }
    for (int i = 64 + eg; i < deg; i += 4) {          // deg > 64 fallback
        int s = csrF[s0 + i];
        float4 hv = bf4_to_f4(*(const uint2*)(h + (size_t)s * C3 + cg * 4));
        float w = __expf(lrelu(as[s] + adv));
        dsum += w;
        acc.x += w * hv.x; acc.y += w * hv.y; acc.z += w * hv.z; acc.w += w * hv.w;
    }
#pragma unroll
    for (int o = 16; o < 64; o <<= 1) {
        acc.x += __shfl_xor(acc.x, o);
        acc.y += __shfl_xor(acc.y, o);
        acc.z += __shfl_xor(acc.z, o);
        acc.w += __shfl_xor(acc.w, o);
        dsum  += __shfl_xor(dsum, o);
    }
    if (eg == 0) {
        float inv = 1.f / (dsum + 1e-16f);
        const float* bp = bias + cg * 4;
        float4 r;
        r.x = acc.x * inv + bp[0];
        r.y = acc.y * inv + bp[1];
        r.z = acc.z * inv + bp[2];
        r.w = acc.w * inv + bp[3];
        *(float4*)(out + (size_t)node * C3 + cg * 4) = r;
    }
}

// ---------------- launch ----------------

extern "C" void kernel_launch(void* const* d_in, const int* in_sizes, int n_in,
                              void* d_out, int out_size, void* d_ws, size_t ws_size,
                              hipStream_t stream) {
    const float* x   = (const float*)d_in[0];
    const int*   ei  = (const int*)d_in[1];
    const float* W1  = (const float*)d_in[2];
    const float* aS1 = (const float*)d_in[3];
    const float* aD1 = (const float*)d_in[4];
    const float* b1  = (const float*)d_in[5];
    const float* W2  = (const float*)d_in[6];
    const float* aS2 = (const float*)d_in[7];
    const float* aD2 = (const float*)d_in[8];
    const float* b2  = (const float*)d_in[9];
    const float* W3  = (const float*)d_in[10];
    const float* aS3 = (const float*)d_in[11];
    const float* aD3 = (const float*)d_in[12];
    const float* b3  = (const float*)d_in[13];
    float* out = (float*)d_out;

    char* p = (char*)d_ws;
    auto alloc = [&](size_t bytes) -> void* {
        void* r = (void*)p;
        p += (bytes + 255) & ~(size_t)255;
        return r;
    };
    u16*   h1b  = (u16*)alloc((size_t)N_NODES * D1 * 2);
    u16*   x2b  = (u16*)alloc((size_t)N_NODES * D1 * 2);
    u16*   h2b  = (u16*)alloc((size_t)N_NODES * C2 * 2);
    u16*   x3b  = (u16*)alloc((size_t)N_NODES * C2 * 2);
    u16*   h3b  = (u16*)alloc((size_t)N_NODES * C3 * 2);
    int*   cnt  = (int*)alloc((size_t)N_NODES * 4);
    int*   csrF = (int*)alloc((size_t)N_NODES * CAP * 4);
    float* asb  = (float*)alloc((size_t)N_NODES * H1 * 4);
    float* adb  = (float*)alloc((size_t)N_NODES * H1 * 4);
    u16*   W1t  = (u16*)alloc((size_t)F0 * D1 * 2);
    u16*   W2t  = (u16*)alloc((size_t)D1 * C2 * 2);
    u16*   W3t  = (u16*)alloc((size_t)C2 * C3 * 2);

    const int* srcArr = ei;
    const int* dstArr = ei + N_EDGES;

    prep_kernel<<<(N_NODES + 255) / 256, 256, 0, stream>>>(W1, W2, W3, W1t, W2t, W3t, cnt);

    int nb4 = (N_NODES + 3) / 4;
    int mb64 = (N_NODES + 63) / 64;

    // layer 1 gemm with fused edge scatter (gemm blocks FIRST, then 1-edge/thread scatter)
    gemm1_scat<<<GEMMB + SCATB, 512, 0, stream>>>(W1t, x, aS1, aD1, h1b, asb, adb, N_NODES,
                                                  srcArr, dstArr, cnt, csrF);
    agg1_kernel<<<nb4, 256, 0, stream>>>(cnt, csrF, h1b, asb, adb, b1, x2b);

    gemm2_mfma<<<mb64, 256, 0, stream>>>(x2b, W2t, aS2, aD2, h2b, asb, adb, N_NODES);
    agg32_kernel<<<nb4, 256, 0, stream>>>(cnt, csrF, h2b, asb, adb, b2, x3b);

    gemm3_mfma<<<mb64, 256, 0, stream>>>(x3b, W3t, aS3, aD3, h3b, asb, adb, N_NODES);
    agg64_kernel<<<nb4, 256, 0, stream>>>(cnt, csrF, h3b, asb, adb, b3, out);
}